// Round 3
// baseline (279.187 us; speedup 1.0000x reference)
//
#include <hip/hip_runtime.h>

#define N_ITER 100

typedef float f2 __attribute__((ext_vector_type(2)));

// DPP move helper: ctrl must be compile-time constant.
template <int CTRL>
__device__ __forceinline__ float dpp_mov_f32(float x) {
  int r = __builtin_amdgcn_update_dpp(0, __float_as_int(x), CTRL, 0xF, 0xF, true);
  return __int_as_float(r);
}

// Full sum across a 16-lane DPP row via rotations (all lanes end with total).
__device__ __forceinline__ float row16_sum(float s) {
  s += dpp_mov_f32<0x128>(s);  // row_ror:8
  s += dpp_mov_f32<0x124>(s);  // row_ror:4
  s += dpp_mov_f32<0x122>(s);  // row_ror:2
  s += dpp_mov_f32<0x121>(s);  // row_ror:1
  return s;
}

// Sum a packed pair across the 4 16-lane rows of a wave (lane^16, lane^32).
__device__ __forceinline__ f2 dq4_sum2(f2 x) {
#if defined(__has_builtin)
#if __has_builtin(__builtin_amdgcn_permlane16_swap) && __has_builtin(__builtin_amdgcn_permlane32_swap)
  {
    typedef unsigned u2 __attribute__((ext_vector_type(2)));
    u2 ra = __builtin_amdgcn_permlane16_swap(__float_as_uint(x.x), __float_as_uint(x.x), false, false);
    u2 rb = __builtin_amdgcn_permlane16_swap(__float_as_uint(x.y), __float_as_uint(x.y), false, false);
    f2 lo = {__uint_as_float(ra.x), __uint_as_float(rb.x)};
    f2 hi = {__uint_as_float(ra.y), __uint_as_float(rb.y)};
    x = lo + hi;
    ra = __builtin_amdgcn_permlane32_swap(__float_as_uint(x.x), __float_as_uint(x.x), false, false);
    rb = __builtin_amdgcn_permlane32_swap(__float_as_uint(x.y), __float_as_uint(x.y), false, false);
    lo = (f2){__uint_as_float(ra.x), __uint_as_float(rb.x)};
    hi = (f2){__uint_as_float(ra.y), __uint_as_float(rb.y)};
    return lo + hi;
  }
#else
  x.x += __shfl_xor(x.x, 16); x.y += __shfl_xor(x.y, 16);
  x.x += __shfl_xor(x.x, 32); x.y += __shfl_xor(x.y, 32);
  return x;
#endif
#else
  x.x += __shfl_xor(x.x, 16); x.y += __shfl_xor(x.y, 16);
  x.x += __shfl_xor(x.x, 32); x.y += __shfl_xor(x.y, 32);
  return x;
#endif
}

// One block (1024 threads = 16 waves) per matrix. Thread (tx=tid&15, ty=tid>>4)
// owns rows [4*ty, 4*ty+4), cols [16*tx, 16*tx+16). V0 = exp(alpha/tau) frozen
// in registers (packed f32 pairs); only scales evolve:
//   R_i = 1/sum_j V0[ij]*C_j ;  C_j = 1/sum_i V0[ij]*R_i
__global__ __launch_bounds__(1024, 4) void sinkhorn16(const float* __restrict__ alpha,
                                                      float* __restrict__ out) {
  // k-major partial layout (conflict-free everywhere): partial for col
  // 16*x+4*k+m of wave w lives at colpart[w*256 + k*64 + x*4 + m].
  __shared__ float colpart[16 * 256];
  __shared__ float colrcp[256];

  const int tid = threadIdx.x;
  const int tx  = tid & 15;
  const int ty  = tid >> 4;         // 0..63
  const int dq  = (tid >> 4) & 3;   // lane>>4
  const int wv  = tid >> 6;         // 0..15

  const size_t mbase = (size_t)blockIdx.x * (256 * 256);
  const float* A = alpha + mbase;
  float*       O = out + mbase;

  f2 v[4][8];  // 4 rows x 16 cols, packed pairs

  // Load + exp(alpha/TAU); 1/0.1f is exactly 10.0f.
#pragma unroll
  for (int i = 0; i < 4; ++i) {
    const float4* src = (const float4*)(A + (size_t)(4 * ty + i) * 256 + 16 * tx);
#pragma unroll
    for (int k = 0; k < 4; ++k) {
      float4 x = src[k];
      v[i][2 * k + 0] = (f2){__expf(x.x * 10.0f), __expf(x.y * 10.0f)};
      v[i][2 * k + 1] = (f2){__expf(x.z * 10.0f), __expf(x.w * 10.0f)};
    }
  }

  f2 C[8];
  float R[4];
#pragma unroll
  for (int j = 0; j < 8; ++j) C[j] = (f2){1.0f, 1.0f};

  for (int it = 0; it < N_ITER; ++it) {
    // ---------- row phase: R_i = 1/sum_j V0[ij]*C_j  (no LDS) ----------
#pragma unroll
    for (int i = 0; i < 4; ++i) {
      f2 a0 = v[i][0] * C[0];
      f2 a1 = v[i][1] * C[1];
#pragma unroll
      for (int m = 1; m < 4; ++m) {
        a0 += v[i][2 * m + 0] * C[2 * m + 0];
        a1 += v[i][2 * m + 1] * C[2 * m + 1];
      }
      f2 a = a0 + a1;
      float s = row16_sum(a.x + a.y);         // sum over the 16 tx threads
      R[i] = __builtin_amdgcn_rcpf(s);
    }

    // ---------- col phase: C_j = 1/sum_i V0[ij]*R_i ----------
    f2 p[8];
#pragma unroll
    for (int j = 0; j < 8; ++j) {
      f2 b0 = v[0][j] * (f2){R[0], R[0]};
      f2 b1 = v[1][j] * (f2){R[1], R[1]};
      b0 += v[2][j] * (f2){R[2], R[2]};
      b1 += v[3][j] * (f2){R[3], R[3]};
      p[j] = dq4_sum2(b0 + b1);  // sum over the wave's 4 row-groups (16 rows)
    }

    if (dq == 0) {  // 16 lanes per wave write the wave's 256 col partials
      float* dst = &colpart[wv * 256 + tx * 4];
#pragma unroll
      for (int k = 0; k < 4; ++k)
        *((float4*)(dst + k * 64)) =
            make_float4(p[2 * k].x, p[2 * k].y, p[2 * k + 1].x, p[2 * k + 1].y);
    }
    __syncthreads();

    if (tid < 64) {  // one wave: sum 16 wave-partials per col (b128, conflict-free)
      const int a = (tid & 3) * 64 + (tid >> 2) * 4;
      float4 s0 = *((const float4*)&colpart[a]);
      f2 lo = (f2){s0.x, s0.y}, hi = (f2){s0.z, s0.w};
#pragma unroll
      for (int w = 1; w < 16; ++w) {
        float4 t = *((const float4*)&colpart[w * 256 + a]);
        lo += (f2){t.x, t.y};
        hi += (f2){t.z, t.w};
      }
      float4 r;
      r.x = __builtin_amdgcn_rcpf(lo.x);
      r.y = __builtin_amdgcn_rcpf(lo.y);
      r.z = __builtin_amdgcn_rcpf(hi.x);
      r.w = __builtin_amdgcn_rcpf(hi.y);
      *((float4*)&colrcp[a]) = r;
    }
    __syncthreads();

    // broadcast C back (k-major: conflict-free)
#pragma unroll
    for (int k = 0; k < 4; ++k) {
      float4 rc = *((const float4*)(&colrcp[k * 64 + tx * 4]));
      C[2 * k + 0] = (f2){rc.x, rc.y};
      C[2 * k + 1] = (f2){rc.z, rc.w};
    }
  }

  // ---------- epilogue: out = V0 * R_i * C_j ----------
#pragma unroll
  for (int i = 0; i < 4; ++i) {
    const f2 Ri = (f2){R[i], R[i]};
    float4* dst = (float4*)(O + (size_t)(4 * ty + i) * 256 + 16 * tx);
#pragma unroll
    for (int k = 0; k < 4; ++k) {
      f2 lo = v[i][2 * k + 0] * Ri * C[2 * k + 0];
      f2 hi = v[i][2 * k + 1] * Ri * C[2 * k + 1];
      dst[k] = make_float4(lo.x, lo.y, hi.x, hi.y);
    }
  }
}

extern "C" void kernel_launch(void* const* d_in, const int* in_sizes, int n_in,
                              void* d_out, int out_size, void* d_ws, size_t ws_size,
                              hipStream_t stream) {
  const float* alpha = (const float*)d_in[0];
  float* out = (float*)d_out;
  sinkhorn16<<<dim3(16), dim3(1024), 0, stream>>>(alpha, out);
}

// Round 4
// 214.925 us; speedup vs baseline: 1.2990x; 1.2990x over previous
//
#include <hip/hip_runtime.h>

#define N_ITER 100

typedef float f2 __attribute__((ext_vector_type(2)));

// Guaranteed-packed fp32 pair math (VOP3P). The compiler did not form these
// from ext-vector ops in R3; force them.
__device__ __forceinline__ f2 pk_mul(f2 a, f2 b) {
  f2 d;
  asm("v_pk_mul_f32 %0, %1, %2" : "=v"(d) : "v"(a), "v"(b));
  return d;
}
__device__ __forceinline__ f2 pk_fma(f2 a, f2 b, f2 c) {
  f2 d;
  asm("v_pk_fma_f32 %0, %1, %2, %3" : "=v"(d) : "v"(a), "v"(b), "v"(c));
  return d;
}
__device__ __forceinline__ f2 pk_add(f2 a, f2 b) {
  f2 d;
  asm("v_pk_add_f32 %0, %1, %2" : "=v"(d) : "v"(a), "v"(b));
  return d;
}

// DPP move helper: ctrl must be compile-time constant.
template <int CTRL>
__device__ __forceinline__ float dpp_mov_f32(float x) {
  int r = __builtin_amdgcn_update_dpp(0, __float_as_int(x), CTRL, 0xF, 0xF, true);
  return __int_as_float(r);
}

// Full sum across a 16-lane DPP row via rotations (all lanes end with total).
__device__ __forceinline__ float row16_sum(float s) {
  s += dpp_mov_f32<0x128>(s);  // row_ror:8
  s += dpp_mov_f32<0x124>(s);  // row_ror:4
  s += dpp_mov_f32<0x122>(s);  // row_ror:2
  s += dpp_mov_f32<0x121>(s);  // row_ror:1
  return s;
}

// Sum a packed pair across the 4 16-lane rows of a wave (lane^16, lane^32).
__device__ __forceinline__ f2 dq4_sum2(f2 x) {
#if defined(__has_builtin)
#if __has_builtin(__builtin_amdgcn_permlane16_swap) && __has_builtin(__builtin_amdgcn_permlane32_swap)
  {
    typedef unsigned u2 __attribute__((ext_vector_type(2)));
    u2 ra = __builtin_amdgcn_permlane16_swap(__float_as_uint(x.x), __float_as_uint(x.x), false, false);
    u2 rb = __builtin_amdgcn_permlane16_swap(__float_as_uint(x.y), __float_as_uint(x.y), false, false);
    f2 lo = {__uint_as_float(ra.x), __uint_as_float(rb.x)};
    f2 hi = {__uint_as_float(ra.y), __uint_as_float(rb.y)};
    x = pk_add(lo, hi);
    ra = __builtin_amdgcn_permlane32_swap(__float_as_uint(x.x), __float_as_uint(x.x), false, false);
    rb = __builtin_amdgcn_permlane32_swap(__float_as_uint(x.y), __float_as_uint(x.y), false, false);
    lo = (f2){__uint_as_float(ra.x), __uint_as_float(rb.x)};
    hi = (f2){__uint_as_float(ra.y), __uint_as_float(rb.y)};
    return pk_add(lo, hi);
  }
#else
  x.x += __shfl_xor(x.x, 16); x.y += __shfl_xor(x.y, 16);
  x.x += __shfl_xor(x.x, 32); x.y += __shfl_xor(x.y, 32);
  return x;
#endif
#else
  x.x += __shfl_xor(x.x, 16); x.y += __shfl_xor(x.y, 16);
  x.x += __shfl_xor(x.x, 32); x.y += __shfl_xor(x.y, 32);
  return x;
#endif
}

// One block (512 threads) per matrix. Thread (tx=tid&15, ty=tid>>4) owns
// rows [8*ty, 8*ty+8), cols [16*tx, 16*tx+16). V0 = exp(alpha/tau) frozen in
// arch VGPRs (waves_per_eu(2,2) gives a 256-reg budget so nothing shunts to
// AGPRs); only scales evolve:
//   R_i = 1/sum_j V0[ij]*C_j ;  C_j = 1/sum_i V0[ij]*R_i
__global__ __launch_bounds__(512, 2)
__attribute__((amdgpu_waves_per_eu(2, 2)))
void sinkhorn16(const float* __restrict__ alpha, float* __restrict__ out) {
  // k-major partial layout: partial for col 16*x+4*k+m of wave w lives at
  // colpart[w*256 + k*64 + x*4 + m]  -> all LDS phases conflict-free
  // (verified: SQ_LDS_BANK_CONFLICT == 0 in R2 with this exact layout).
  __shared__ float colpart[8 * 256];
  __shared__ float colrcp[256];

  const int tid = threadIdx.x;
  const int tx  = tid & 15;
  const int ty  = tid >> 4;         // 0..31
  const int dq  = (tid >> 4) & 3;   // lane>>4
  const int wv  = tid >> 6;         // 0..7

  const size_t mbase = (size_t)blockIdx.x * (256 * 256);
  const float* A = alpha + mbase;
  float*       O = out + mbase;

  f2 v[8][8];  // 8 rows x 16 cols, packed pairs (128 VGPRs)

  // Load + exp(alpha/TAU); 1/0.1f is exactly 10.0f.
#pragma unroll
  for (int i = 0; i < 8; ++i) {
    const float4* src = (const float4*)(A + (size_t)(8 * ty + i) * 256 + 16 * tx);
#pragma unroll
    for (int k = 0; k < 4; ++k) {
      float4 x = src[k];
      v[i][2 * k + 0] = (f2){__expf(x.x * 10.0f), __expf(x.y * 10.0f)};
      v[i][2 * k + 1] = (f2){__expf(x.z * 10.0f), __expf(x.w * 10.0f)};
    }
  }

  f2 C[8];
  float R[8];
#pragma unroll
  for (int j = 0; j < 8; ++j) C[j] = (f2){1.0f, 1.0f};

  for (int it = 0; it < N_ITER; ++it) {
    // ---------- row phase: R_i = 1/sum_j V0[ij]*C_j  (no LDS) ----------
#pragma unroll
    for (int i = 0; i < 8; ++i) {
      f2 a0 = pk_mul(v[i][0], C[0]);
      f2 a1 = pk_mul(v[i][1], C[1]);
#pragma unroll
      for (int m = 1; m < 4; ++m) {
        a0 = pk_fma(v[i][2 * m + 0], C[2 * m + 0], a0);
        a1 = pk_fma(v[i][2 * m + 1], C[2 * m + 1], a1);
      }
      f2 a = pk_add(a0, a1);
      float s = row16_sum(a.x + a.y);  // sum over the 16 tx threads
      R[i] = __builtin_amdgcn_rcpf(s);
    }

    // ---------- col phase: C_j = 1/sum_i V0[ij]*R_i ----------
    f2 RR[8];
#pragma unroll
    for (int i = 0; i < 8; ++i) RR[i] = (f2){R[i], R[i]};

    f2 p[8];
#pragma unroll
    for (int j = 0; j < 8; ++j) {
      f2 b0 = pk_mul(v[0][j], RR[0]);
      f2 b1 = pk_mul(v[1][j], RR[1]);
#pragma unroll
      for (int i = 1; i < 4; ++i) {
        b0 = pk_fma(v[2 * i + 0][j], RR[2 * i + 0], b0);
        b1 = pk_fma(v[2 * i + 1][j], RR[2 * i + 1], b1);
      }
      p[j] = dq4_sum2(pk_add(b0, b1));  // sum over the wave's 4 row-groups
    }

    if (dq == 0) {  // 16 lanes per wave write the wave's 256 col partials
      float* dst = &colpart[wv * 256 + tx * 4];
#pragma unroll
      for (int k = 0; k < 4; ++k)
        *((float4*)(dst + k * 64)) =
            make_float4(p[2 * k].x, p[2 * k].y, p[2 * k + 1].x, p[2 * k + 1].y);
    }
    __syncthreads();

    if (tid < 256) {  // sum 8 wave-partials per col, reciprocal (conflict-free)
      float c0 = colpart[0 * 256 + tid] + colpart[1 * 256 + tid];
      float c1 = colpart[2 * 256 + tid] + colpart[3 * 256 + tid];
      float c2 = colpart[4 * 256 + tid] + colpart[5 * 256 + tid];
      float c3 = colpart[6 * 256 + tid] + colpart[7 * 256 + tid];
      colrcp[tid] = __builtin_amdgcn_rcpf((c0 + c1) + (c2 + c3));
    }
    __syncthreads();

    // broadcast C back (k-major: conflict-free)
#pragma unroll
    for (int k = 0; k < 4; ++k) {
      float4 rc = *((const float4*)(&colrcp[k * 64 + tx * 4]));
      C[2 * k + 0] = (f2){rc.x, rc.y};
      C[2 * k + 1] = (f2){rc.z, rc.w};
    }
  }

  // ---------- epilogue: out = V0 * R_i * C_j ----------
#pragma unroll
  for (int i = 0; i < 8; ++i) {
    const f2 Ri = (f2){R[i], R[i]};
    float4* dst = (float4*)(O + (size_t)(8 * ty + i) * 256 + 16 * tx);
#pragma unroll
    for (int k = 0; k < 4; ++k) {
      f2 lo = pk_mul(pk_mul(v[i][2 * k + 0], Ri), C[2 * k + 0]);
      f2 hi = pk_mul(pk_mul(v[i][2 * k + 1], Ri), C[2 * k + 1]);
      dst[k] = make_float4(lo.x, lo.y, hi.x, hi.y);
    }
  }
}

extern "C" void kernel_launch(void* const* d_in, const int* in_sizes, int n_in,
                              void* d_out, int out_size, void* d_ws, size_t ws_size,
                              hipStream_t stream) {
  const float* alpha = (const float*)d_in[0];
  float* out = (float*)d_out;
  sinkhorn16<<<dim3(16), dim3(512), 0, stream>>>(alpha, out);
}